// Round 2
// baseline (255.119 us; speedup 1.0000x reference)
//
#include <hip/hip_runtime.h>
#include <hip/hip_bf16.h>
#include <stdint.h>

// QuantizedLinear: out[16,11008] = x[16,4096] @ ((W - zp)*scale)^T
// HARNESS NOTE: integer inputs are materialized as int32 ("integer -> const
// int*"), so W is a 180 MB int32 buffer. Roofline = 180 MB / 6.3 TB/s ~ 29 us.
// Strategy: stream W as int32, pack low bytes in-register to i8 MFMA B-frags;
// x quantized to hi/lo int8 planes (15-bit effective precision).

#define M_TOK 16
#define K_DIM 4096
#define N_OUT 11008

typedef int v4i __attribute__((ext_vector_type(4)));

// ---------------- Kernel 1: per-token quantization of x ----------------
// ws layout: xh[16*4096] | xl[16*4096] | s1[16] | sumx[16]
__global__ __launch_bounds__(256) void quant_x_kernel(
    const float* __restrict__ x, int8_t* __restrict__ xh,
    int8_t* __restrict__ xl, float* __restrict__ s1_out,
    float* __restrict__ sumx_out) {
  const int t = blockIdx.x;      // token
  const int tid = threadIdx.x;   // 256 threads, 16 consecutive elems each
  const float4* xv = (const float4*)(x + (long)t * K_DIM) + tid * 4;

  float vals[16];
  float m = 0.0f, s = 0.0f;
#pragma unroll
  for (int j = 0; j < 4; ++j) {
    float4 f = xv[j];
    vals[j * 4 + 0] = f.x; vals[j * 4 + 1] = f.y;
    vals[j * 4 + 2] = f.z; vals[j * 4 + 3] = f.w;
    m = fmaxf(m, fmaxf(fmaxf(fabsf(f.x), fabsf(f.y)),
                       fmaxf(fabsf(f.z), fabsf(f.w))));
    s += f.x + f.y + f.z + f.w;
  }
#pragma unroll
  for (int off = 32; off > 0; off >>= 1) {
    m = fmaxf(m, __shfl_xor(m, off));
    s += __shfl_xor(s, off);
  }
  __shared__ float lm[4], ls[4];
  const int w = tid >> 6;
  if ((tid & 63) == 0) { lm[w] = m; ls[w] = s; }
  __syncthreads();
  m = fmaxf(fmaxf(lm[0], lm[1]), fmaxf(lm[2], lm[3]));
  s = ls[0] + ls[1] + ls[2] + ls[3];

  const float s1 = (m > 0.0f) ? (m * (1.0f / 127.0f)) : 1.0f;
  const float inv = 1.0f / s1;
  if (tid == 0) { s1_out[t] = s1; sumx_out[t] = s; }

  int hq[16], lq[16];
#pragma unroll
  for (int j = 0; j < 16; ++j) {
    float xf = vals[j];
    float h = rintf(xf * inv);
    h = fminf(fmaxf(h, -127.0f), 127.0f);
    float resid = xf - h * s1;
    float l = rintf(resid * inv * 256.0f);
    l = fminf(fmaxf(l, -128.0f), 127.0f);
    hq[j] = (int)h;
    lq[j] = (int)l;
  }
  int4 hv, lv;
  int* hp = (int*)&hv;
  int* lp = (int*)&lv;
#pragma unroll
  for (int d = 0; d < 4; ++d) {
    uint32_t hw = 0, lw = 0;
#pragma unroll
    for (int j = 0; j < 4; ++j) {
      hw |= (uint32_t)(hq[d * 4 + j] & 0xff) << (8 * j);
      lw |= (uint32_t)(lq[d * 4 + j] & 0xff) << (8 * j);
    }
    hp[d] = (int)hw;
    lp[d] = (int)lw;
  }
  ((int4*)xh)[(long)t * 256 + tid] = hv;
  ((int4*)xl)[(long)t * 256 + tid] = lv;
}

// ---------------- Kernel 2: weight-streaming i8 MFMA GEMM ----------------
// Block = 256 thr (4 waves), 16 output rows/block, wave w owns K range
// [w*1024, +1024). Per 64-k chunk a lane loads 16 int32 weights (64 B, four
// dwordx4), packs low bytes into the 16-int8 B fragment. A hi/lo fragments
// come from the L2-resident x planes. LDS only for the 4-way K reduction.
__global__ __launch_bounds__(256) void qgemm_kernel(
    const int* __restrict__ W, const int8_t* __restrict__ xh,
    const int8_t* __restrict__ xl, const float* __restrict__ s1,
    const float* __restrict__ sumx, const float* __restrict__ scale_p,
    const int* __restrict__ zp_p, float* __restrict__ out) {
  const int tid = threadIdx.x;
  const int lane = tid & 63;
  const int w = tid >> 6;          // wave id = K split
  const int obase = blockIdx.x * 16;
  const int n = lane & 15;         // output-row (B col) / token (A row)
  const int g = lane >> 4;         // k sub-group within 64-k chunk
  const long kbase = (long)w * 1024 + g * 16;

  const int* Wp = W + (long)(obase + n) * K_DIM + kbase;  // int32 elements
  const v4i* Ah = (const v4i*)(xh + (long)n * K_DIM + kbase);
  const v4i* Al = (const v4i*)(xl + (long)n * K_DIM + kbase);

  v4i accH = {0, 0, 0, 0};
  v4i accL = {0, 0, 0, 0};
#pragma unroll 4
  for (int c = 0; c < 16; ++c) {   // 16 chunks x 64 k = 1024
    const int4* wq = (const int4*)(Wp + c * 64);
    v4i b;
#pragma unroll
    for (int d = 0; d < 4; ++d) {
      int4 q = wq[d];
      uint32_t packed = ((uint32_t)q.x & 0xffu) |
                        (((uint32_t)q.y & 0xffu) << 8) |
                        (((uint32_t)q.z & 0xffu) << 16) |
                        (((uint32_t)q.w & 0xffu) << 24);
      b[d] = (int)packed;
    }
    v4i ah = Ah[c * 4];
    v4i al = Al[c * 4];
    accH = __builtin_amdgcn_mfma_i32_16x16x64_i8(ah, b, accH, 0, 0, 0);
    accL = __builtin_amdgcn_mfma_i32_16x16x64_i8(al, b, accL, 0, 0, 0);
  }

  // C layout (16x16): col = lane&15 (=o), row = (lane>>4)*4 + reg (=token)
  __shared__ float red[4][16 * 17];
#pragma unroll
  for (int r = 0; r < 4; ++r) {
    float f = (float)accH[r] + (float)accL[r] * (1.0f / 256.0f);
    int t = g * 4 + r;
    red[w][t * 17 + n] = f;
  }
  __syncthreads();

  const int t = tid >> 4;
  const int col = tid & 15;
  float sum = red[0][t * 17 + col] + red[1][t * 17 + col] +
              red[2][t * 17 + col] + red[3][t * 17 + col];
  const float sc = scale_p[0];
  const float zp = (float)zp_p[0];
  float o = sc * (s1[t] * sum) - sc * zp * sumx[t];
  out[(long)t * N_OUT + obase + col] = o;
}

extern "C" void kernel_launch(void* const* d_in, const int* in_sizes, int n_in,
                              void* d_out, int out_size, void* d_ws,
                              size_t ws_size, hipStream_t stream) {
  const float* x = (const float*)d_in[0];
  const int* Wq = (const int*)d_in[1];          // int inputs come as int32
  const float* scale_p = (const float*)d_in[2];
  const int* zp_p = (const int*)d_in[3];
  float* out = (float*)d_out;

  int8_t* xh = (int8_t*)d_ws;
  int8_t* xl = xh + (long)M_TOK * K_DIM;
  float* s1 = (float*)(xl + (long)M_TOK * K_DIM);
  float* sumx = s1 + M_TOK;

  quant_x_kernel<<<M_TOK, 256, 0, stream>>>(x, xh, xl, s1, sumx);
  qgemm_kernel<<<N_OUT / 16, 256, 0, stream>>>(Wq, xh, xl, s1, sumx, scale_p,
                                               zp_p, out);
}